// Round 2
// baseline (221.147 us; speedup 1.0000x reference)
//
#include <hip/hip_runtime.h>

#define HID 4096
#define MD  128
#define SB  32768          // B*S rows total
#define SLEN 4096
#define NB  8
#define NH  10
#define WIN 10
#define TLEN (SLEN - WIN + 1)   // 4087
#define NEGV -1000000000.0f

typedef _Float16 f16x8 __attribute__((ext_vector_type(8)));
typedef float f32x4 __attribute__((ext_vector_type(4)));

__device__ __forceinline__ unsigned short f2h(float f) {
  _Float16 h = (_Float16)f;
  return __builtin_bit_cast(unsigned short, h);
}

__device__ __forceinline__ f16x8 cvt8(float4 u, float4 v) {
  f16x8 r;
  r[0] = (_Float16)u.x; r[1] = (_Float16)u.y; r[2] = (_Float16)u.z; r[3] = (_Float16)u.w;
  r[4] = (_Float16)v.x; r[5] = (_Float16)v.y; r[6] = (_Float16)v.z; r[7] = (_Float16)v.w;
  return r;
}

// ---------------- weight preconvert: fp32 -> fp16 planes in ws ----------------
__global__ void convert_k(const float* __restrict__ W1, const float* __restrict__ W2,
                          const float* __restrict__ Wq, const float* __restrict__ Wv,
                          unsigned short* __restrict__ w1h, unsigned short* __restrict__ w2h,
                          unsigned short* __restrict__ wqvh) {
  int i = blockIdx.x * 256 + threadIdx.x;
  if (i < MD * HID) w1h[i] = f2h(W1[i]);
  if (i < MD * MD)  w2h[i] = f2h(W2[i]);
  if (i < 32 * MD) {                       // 32 padded rows: 0-9 Wq, 10-19 Wv, 20-31 zero
    unsigned short v = 0;
    if (i < NH * MD)          v = f2h(Wq[i]);
    else if (i < 2 * NH * MD) v = f2h(Wv[i - NH * MD]);
    wqvh[i] = v;
  }
}

// ---------------- fused MLP + heads: barrier-free streaming ----------------
// grid 256 blocks x 256 thr; each wave owns 32 rows x full N=128.
// A (x) and B (W1/W2/Wqv fp16) fragments loaded directly from global.
// Per-wave 8KB LDS scratch only for the layer1->2->3 fragment re-layouts.
__global__ __launch_bounds__(256, 1) void fused_mlp(
    const float* __restrict__ x,
    const float* __restrict__ b1g, const float* __restrict__ b2g,
    const float* __restrict__ bvg,
    const unsigned short* __restrict__ w1h, const unsigned short* __restrict__ w2h,
    const unsigned short* __restrict__ wqvh,
    float* __restrict__ lv)
{
  __shared__ __align__(16) char Ysm[4][8192];
  const int tid  = threadIdx.x;
  const int lane = tid & 63;
  const int w    = tid >> 6;
  const int l15  = lane & 15;
  const int j    = lane >> 4;          // quarter-wave index
  char* Y = Ysm[w];
  const int r0 = (blockIdx.x * 4 + w) * 32;

  const float* xb0 = x + (size_t)(r0 + l15) * HID + j * 8;
  const float* xb1 = x + (size_t)(r0 + 16 + l15) * HID + j * 8;
  const unsigned short* w1b = w1h + (size_t)l15 * HID + j * 8;

  f32x4 acc0[8] = {}, acc1[8] = {};

  // main loop: K = 4096 in 32 steps of BK=128. No LDS, no barriers.
  for (int kt = 0; kt < 32; ++kt) {
    const int k0 = kt * 128;
    float4 av0[8], av1[8];
    #pragma unroll
    for (int ks = 0; ks < 4; ++ks) {
      av0[ks * 2 + 0] = *(const float4*)(xb0 + k0 + ks * 32);
      av0[ks * 2 + 1] = *(const float4*)(xb0 + k0 + ks * 32 + 4);
      av1[ks * 2 + 0] = *(const float4*)(xb1 + k0 + ks * 32);
      av1[ks * 2 + 1] = *(const float4*)(xb1 + k0 + ks * 32 + 4);
    }
    f16x8 af0[4], af1[4];
    #pragma unroll
    for (int ks = 0; ks < 4; ++ks) {
      af0[ks] = cvt8(av0[ks * 2], av0[ks * 2 + 1]);
      af1[ks] = cvt8(av1[ks * 2], av1[ks * 2 + 1]);
    }
    #pragma unroll
    for (int ks = 0; ks < 4; ++ks) {
      #pragma unroll
      for (int nf = 0; nf < 8; ++nf) {
        f16x8 bf = *(const f16x8*)(w1b + (size_t)nf * 16 * HID + k0 + ks * 32);
        acc0[nf] = __builtin_amdgcn_mfma_f32_16x16x32_f16(af0[ks], bf, acc0[nf], 0, 0, 0);
        acc1[nf] = __builtin_amdgcn_mfma_f32_16x16x32_f16(af1[ks], bf, acc1[nf], 0, 0, 0);
      }
    }
  }

  // ---- y1 = relu(acc + b1) -> Y (fp16 [32 rows][256B], XOR-swizzled) ----
  #pragma unroll
  for (int nf = 0; nf < 8; ++nf) {
    const int col = nf * 16 + l15;
    const float bb = b1g[col];
    #pragma unroll
    for (int r = 0; r < 4; ++r) {
      int row = j * 4 + r;
      float t0 = acc0[nf][r] + bb; t0 = t0 > 0.f ? t0 : 0.f;
      *(unsigned short*)(Y + row * 256 + ((col * 2) ^ ((row & 7) << 4))) = f2h(t0);
      int row1 = 16 + row;
      float t1 = acc1[nf][r] + bb; t1 = t1 > 0.f ? t1 : 0.f;
      *(unsigned short*)(Y + row1 * 256 + ((col * 2) ^ ((row1 & 7) << 4))) = f2h(t1);
    }
  }

  // ---- layer 2: y2 = relu(y1 @ W2^T + b2), K=128, W2 frags from global ----
  f16x8 a20[4], a21[4];
  #pragma unroll
  for (int ks = 0; ks < 4; ++ks) {
    int kb = ks * 64 + j * 16;
    int row = l15;
    a20[ks] = *(const f16x8*)(Y + row * 256 + (kb ^ ((row & 7) << 4)));
    int row1 = 16 + l15;
    a21[ks] = *(const f16x8*)(Y + row1 * 256 + (kb ^ ((row1 & 7) << 4)));
  }
  f32x4 acc2a[8] = {}, acc2b[8] = {};
  const unsigned short* w2b = w2h + l15 * MD + j * 8;
  #pragma unroll
  for (int ks = 0; ks < 4; ++ks) {
    #pragma unroll
    for (int nf = 0; nf < 8; ++nf) {
      f16x8 bf = *(const f16x8*)(w2b + nf * 16 * MD + ks * 32);
      acc2a[nf] = __builtin_amdgcn_mfma_f32_16x16x32_f16(a20[ks], bf, acc2a[nf], 0, 0, 0);
      acc2b[nf] = __builtin_amdgcn_mfma_f32_16x16x32_f16(a21[ks], bf, acc2b[nf], 0, 0, 0);
    }
  }
  #pragma unroll
  for (int nf = 0; nf < 8; ++nf) {
    const int col = nf * 16 + l15;
    const float bb = b2g[col];
    #pragma unroll
    for (int r = 0; r < 4; ++r) {
      int row = j * 4 + r;
      float t0 = acc2a[nf][r] + bb; t0 = t0 > 0.f ? t0 : 0.f;
      *(unsigned short*)(Y + row * 256 + ((col * 2) ^ ((row & 7) << 4))) = f2h(t0);
      int row1 = 16 + row;
      float t1 = acc2b[nf][r] + bb; t1 = t1 > 0.f ? t1 : 0.f;
      *(unsigned short*)(Y + row1 * 256 + ((col * 2) ^ ((row1 & 7) << 4))) = f2h(t1);
    }
  }

  // ---- layer 3: heads (N=32 padded, 20 valid), Wqv frags from global ----
  f16x8 a30[4], a31[4];
  #pragma unroll
  for (int ks = 0; ks < 4; ++ks) {
    int kb = ks * 64 + j * 16;
    int row = l15;
    a30[ks] = *(const f16x8*)(Y + row * 256 + (kb ^ ((row & 7) << 4)));
    int row1 = 16 + l15;
    a31[ks] = *(const f16x8*)(Y + row1 * 256 + (kb ^ ((row1 & 7) << 4)));
  }
  f32x4 acc3a[2] = {}, acc3b[2] = {};
  const unsigned short* wqb = wqvh + l15 * MD + j * 8;
  #pragma unroll
  for (int ks = 0; ks < 4; ++ks) {
    #pragma unroll
    for (int nt = 0; nt < 2; ++nt) {
      f16x8 bf = *(const f16x8*)(wqb + nt * 16 * MD + ks * 32);
      acc3a[nt] = __builtin_amdgcn_mfma_f32_16x16x32_f16(a30[ks], bf, acc3a[nt], 0, 0, 0);
      acc3b[nt] = __builtin_amdgcn_mfma_f32_16x16x32_f16(a31[ks], bf, acc3b[nt], 0, 0, 0);
    }
  }
  #pragma unroll
  for (int nt = 0; nt < 2; ++nt) {
    const int col = nt * 16 + l15;
    if (col < 2 * NH) {
      const float badd = (col < NH) ? 0.f : bvg[col - NH];
      const size_t plane = (size_t)col * SB;
      #pragma unroll
      for (int r = 0; r < 4; ++r) {
        int s0 = r0 + j * 4 + r;
        lv[plane + s0]      = acc3a[nt][r] + badd;
        lv[plane + s0 + 16] = acc3b[nt][r] + badd;
      }
    }
  }
}

// ---------------- sliding-window softmax + per-chunk max ----------------
// grid (16 chunks, 8 batch, 10 heads) x 256 thr
__global__ void windows_k(const float* __restrict__ lv, const int* __restrict__ mask,
                          float* __restrict__ partial) {
  const int chunk = blockIdx.x, b = blockIdx.y, h = blockIdx.z;
  const int t0 = chunk * 256;
  const int tid = threadIdx.x;
  __shared__ float lsh[272], vsh[272];
  const float* lp = lv + (size_t)h * SB + b * SLEN;
  const float* vp = lv + (size_t)(NH + h) * SB + b * SLEN;
  const int* mp = mask + b * SLEN;
  for (int i = tid; i < 256 + WIN - 1; i += 256) {
    int t = t0 + i;
    if (t < SLEN) {
      float l = lp[t];
      if (mp[t] == 0) l = NEGV;
      lsh[i] = l; vsh[i] = vp[t];
    }
  }
  __syncthreads();
  float wmax = -INFINITY;
  int t = t0 + tid;
  if (t < TLEN) {
    float m = lsh[tid];
    #pragma unroll
    for (int j = 1; j < WIN; ++j) m = fmaxf(m, lsh[tid + j]);
    float den = 0.f, num = 0.f;
    #pragma unroll
    for (int j = 0; j < WIN; ++j) {
      float e = __expf(lsh[tid + j] - m);
      den += e; num += e * vsh[tid + j];
    }
    wmax = num / den;
  }
  #pragma unroll
  for (int o = 32; o > 0; o >>= 1) wmax = fmaxf(wmax, __shfl_down(wmax, o, 64));
  __shared__ float red[4];
  if ((tid & 63) == 0) red[tid >> 6] = wmax;
  __syncthreads();
  if (tid == 0) {
    float r = fmaxf(fmaxf(red[0], red[1]), fmaxf(red[2], red[3]));
    partial[(b * NH + h) * 16 + chunk] = r;
  }
}

// ---------------- final: max over chunks, sum heads, + bias ----------------
__global__ void finalize_k(const float* __restrict__ partial, const float* __restrict__ bias,
                           float* __restrict__ out) {
  const int tid = threadIdx.x;  // 1 block, 128 thr
  __shared__ float hm[80];
  if (tid < NB * NH) {
    float m = -INFINITY;
    #pragma unroll
    for (int c = 0; c < 16; ++c) m = fmaxf(m, partial[tid * 16 + c]);
    hm[tid] = m;
  }
  __syncthreads();
  if (tid < NB) {
    float s = bias[0];
    #pragma unroll
    for (int h = 0; h < NH; ++h) s += hm[tid * NH + h];
    out[tid] = s;
  }
}

extern "C" void kernel_launch(void* const* d_in, const int* in_sizes, int n_in,
                              void* d_out, int out_size, void* d_ws, size_t ws_size,
                              hipStream_t stream) {
  const float* x    = (const float*)d_in[0];
  const int*   mask = (const int*)d_in[1];
  const float* W1   = (const float*)d_in[2];
  const float* b1   = (const float*)d_in[3];
  const float* W2   = (const float*)d_in[4];
  const float* b2   = (const float*)d_in[5];
  const float* Wq   = (const float*)d_in[6];
  const float* Wv   = (const float*)d_in[7];
  const float* bv   = (const float*)d_in[8];
  const float* bias = (const float*)d_in[9];

  char* ws = (char*)d_ws;
  unsigned short* w1h  = (unsigned short*)ws;                   // 1,048,576 B
  unsigned short* w2h  = (unsigned short*)(ws + 1048576);       //    32,768 B
  unsigned short* wqvh = (unsigned short*)(ws + 1081344);       //     8,192 B
  float* lv            = (float*)(ws + 1089536);                // 20*32768*4 = 2,621,440 B
  float* partial       = (float*)(ws + 3710976);                //     5,120 B
  float* out = (float*)d_out;

  hipLaunchKernelGGL(convert_k, dim3(2048), dim3(256), 0, stream, W1, W2, Wq, Wv, w1h, w2h, wqvh);
  hipLaunchKernelGGL(fused_mlp, dim3(SB / 128), dim3(256), 0, stream,
                     x, b1, b2, bv, w1h, w2h, wqvh, lv);
  hipLaunchKernelGGL(windows_k, dim3(16, NB, NH), dim3(256), 0, stream, lv, mask, partial);
  hipLaunchKernelGGL(finalize_k, dim3(1), dim3(128), 0, stream, partial, bias, out);
}

// Round 3
// 206.471 us; speedup vs baseline: 1.0711x; 1.0711x over previous
//
#include <hip/hip_runtime.h>

#define HID 4096
#define MD  128
#define SB  32768          // B*S rows total
#define SLEN 4096
#define NB  8
#define NH  10
#define WIN 10
#define TLEN (SLEN - WIN + 1)   // 4087
#define NEGV -1000000000.0f

typedef _Float16 f16x8 __attribute__((ext_vector_type(8)));
typedef float f32x4 __attribute__((ext_vector_type(4)));

__device__ __forceinline__ unsigned short f2h(float f) {
  _Float16 h = (_Float16)f;
  return __builtin_bit_cast(unsigned short, h);
}

__device__ __forceinline__ f16x8 cvt8(float4 u, float4 v) {
  f16x8 r;
  r[0] = (_Float16)u.x; r[1] = (_Float16)u.y; r[2] = (_Float16)u.z; r[3] = (_Float16)u.w;
  r[4] = (_Float16)v.x; r[5] = (_Float16)v.y; r[6] = (_Float16)v.z; r[7] = (_Float16)v.w;
  return r;
}

__device__ __forceinline__ void gl_lds16(const void* g, void* l) {
  __builtin_amdgcn_global_load_lds(
      (const __attribute__((address_space(1))) void*)g,
      (__attribute__((address_space(3))) void*)l, 16, 0, 0);
}

// ---------------- weight preconvert: fp32 -> fp16 planes in ws ----------------
__global__ void convert_k(const float* __restrict__ W1, const float* __restrict__ W2,
                          const float* __restrict__ Wq, const float* __restrict__ Wv,
                          unsigned short* __restrict__ w1h, unsigned short* __restrict__ w2h,
                          unsigned short* __restrict__ wqvh) {
  int i = blockIdx.x * 256 + threadIdx.x;
  if (i < MD * HID) w1h[i] = f2h(W1[i]);
  if (i < MD * MD)  w2h[i] = f2h(W2[i]);
  if (i < 32 * MD) {                       // 32 padded rows: 0-9 Wq, 10-19 Wv, 20-31 zero
    unsigned short v = 0;
    if (i < NH * MD)          v = f2h(Wq[i]);
    else if (i < 2 * NH * MD) v = f2h(Wv[i - NH * MD]);
    wqvh[i] = v;
  }
}

// ---------------- fused MLP + heads ----------------
// grid 1024 x 256 thr (4 waves). Block = 32 rows. Wave (wr,wc): rows wr*16+..,
// cols wc*64+.. of layer-1 output. A (x) loaded straight to registers in MFMA
// fragment layout (2-deep prefetch); B (W1 fp16, L2-resident) via
// global_load_lds double-buffer. 32KB LDS -> 4 blocks/CU.
__global__ __launch_bounds__(256, 4) void fused_mlp(
    const float* __restrict__ x,
    const float* __restrict__ b1g, const float* __restrict__ b2g,
    const float* __restrict__ bvg,
    const unsigned short* __restrict__ w1h, const unsigned short* __restrict__ w2h,
    const unsigned short* __restrict__ wqvh,
    float* __restrict__ lv)
{
  __shared__ __align__(16) char smem[32768];   // B dbuf 2x16KB; Y reuses [0,8KB)
  char* Y = smem;

  const int tid  = threadIdx.x;
  const int lane = tid & 63;
  const int w    = tid >> 6;
  const int wr   = w >> 1, wc = w & 1;
  const int l15  = lane & 15;
  const int j    = lane >> 4;
  const int m0   = blockIdx.x * 32;

  // per-thread B staging geometry (16KB tile = 4 chunks of 256x16B)
  const int tb0   = tid * 16;
  const int brow0 = tb0 >> 7;          // chunk c adds 32 rows
  const int bkb   = tb0 & 127;
  // A stream base
  const float* xb = x + (size_t)(m0 + wr * 16 + l15) * HID + j * 8;

  f32x4 acc[4] = {};
  float4 avA[4], avB[4];
  f16x8 af[2];

#define STAGEB(KT, BUFOFF)                                                     \
  {                                                                            \
    _Pragma("unroll")                                                          \
    for (int c = 0; c < 4; ++c) {                                              \
      int row = brow0 + c * 32;                                                \
      int kbs = bkb ^ ((row & 7) << 4);                                        \
      gl_lds16(w1h + (size_t)row * HID + (KT) * 64 + (kbs >> 1),               \
               smem + (BUFOFF) + c * 4096 + w * 1024);                         \
    }                                                                          \
  }

#define LOADX(AV, KT)                                                          \
  {                                                                            \
    const float* p = xb + (size_t)(KT) * 64;                                   \
    AV[0] = *(const float4*)(p);                                               \
    AV[1] = *(const float4*)(p + 4);                                           \
    AV[2] = *(const float4*)(p + 32);                                          \
    AV[3] = *(const float4*)(p + 36);                                          \
  }

#define CVT(AV) { af[0] = cvt8(AV[0], AV[1]); af[1] = cvt8(AV[2], AV[3]); }

#define DOMFMA(BUFOFF)                                                         \
  {                                                                            \
    f16x8 bf[4][2];                                                            \
    _Pragma("unroll")                                                          \
    for (int nf = 0; nf < 4; ++nf) {                                           \
      int n = wc * 64 + nf * 16 + l15;                                         \
      const char* base = smem + (BUFOFF) + n * 128;                            \
      int sw = (n & 7) << 4;                                                   \
      bf[nf][0] = *(const f16x8*)(base + ((j * 16) ^ sw));                     \
      bf[nf][1] = *(const f16x8*)(base + ((64 + j * 16) ^ sw));                \
    }                                                                          \
    _Pragma("unroll")                                                          \
    for (int ks = 0; ks < 2; ++ks)                                             \
      _Pragma("unroll")                                                        \
      for (int nf = 0; nf < 4; ++nf)                                           \
        acc[nf] = __builtin_amdgcn_mfma_f32_16x16x32_f16(af[ks], bf[nf][ks],   \
                                                         acc[nf], 0, 0, 0);    \
  }

  // prologue
  STAGEB(0, 0);
  LOADX(avA, 0);
  LOADX(avB, 1);
  CVT(avA);                 // af <- x(0)
  __syncthreads();          // B(0) staged

  #pragma unroll 1
  for (int kt = 0; kt < 64; kt += 2) {
    // phase A: compute kt (B in buf0)
    if (kt + 2 < 64) LOADX(avA, kt + 2);
    STAGEB(kt + 1, 16384);
    DOMFMA(0);
    CVT(avB);               // af <- x(kt+1)
    __syncthreads();        // B(kt+1) staged (+ x(kt+2) drained)
    // phase B: compute kt+1 (B in buf1)
    if (kt + 3 < 64) LOADX(avB, kt + 3);
    if (kt + 2 < 64) STAGEB(kt + 2, 0);
    DOMFMA(16384);
    if (kt + 2 < 64) CVT(avA);  // af <- x(kt+2)
    __syncthreads();
  }

  // ---- y1 = relu(acc + b1) -> Y fp16 [32][256B] XOR-swizzled ----
  #pragma unroll
  for (int nf = 0; nf < 4; ++nf) {
    const int col = wc * 64 + nf * 16 + l15;
    const float bb = b1g[col];
    #pragma unroll
    for (int r = 0; r < 4; ++r) {
      int row = wr * 16 + j * 4 + r;
      float t = acc[nf][r] + bb; t = t > 0.f ? t : 0.f;
      *(unsigned short*)(Y + row * 256 + ((col * 2) ^ ((row & 7) << 4))) = f2h(t);
    }
  }
  __syncthreads();

  // ---- layer 2: y2 = relu(y1 @ W2^T + b2), K=128; W2 frags from L2 ----
  f16x8 a2[4];
  {
    const int row = wr * 16 + l15;
    const char* base = Y + row * 256;
    const int sw = (row & 7) << 4;
    #pragma unroll
    for (int ks = 0; ks < 4; ++ks)
      a2[ks] = *(const f16x8*)(base + ((ks * 64 + j * 16) ^ sw));
  }
  f32x4 acc2[4] = {};
  const unsigned short* w2b = w2h + (size_t)(wc * 64 + l15) * MD + j * 8;
  #pragma unroll
  for (int ks = 0; ks < 4; ++ks)
    #pragma unroll
    for (int nf = 0; nf < 4; ++nf) {
      f16x8 bf = *(const f16x8*)(w2b + (size_t)nf * 16 * MD + ks * 32);
      acc2[nf] = __builtin_amdgcn_mfma_f32_16x16x32_f16(a2[ks], bf, acc2[nf], 0, 0, 0);
    }
  __syncthreads();   // Y reads done
  #pragma unroll
  for (int nf = 0; nf < 4; ++nf) {
    const int col = wc * 64 + nf * 16 + l15;
    const float bb = b2g[col];
    #pragma unroll
    for (int r = 0; r < 4; ++r) {
      int row = wr * 16 + j * 4 + r;
      float t = acc2[nf][r] + bb; t = t > 0.f ? t : 0.f;
      *(unsigned short*)(Y + row * 256 + ((col * 2) ^ ((row & 7) << 4))) = f2h(t);
    }
  }
  __syncthreads();

  // ---- layer 3: heads (N=32 padded, 20 valid). wave w: rows (w&1)*16.., cols (w>>1)*16.. ----
  const int rh = w & 1, nt = w >> 1;
  f16x8 a3[4];
  {
    const int row = rh * 16 + l15;
    const char* base = Y + row * 256;
    const int sw = (row & 7) << 4;
    #pragma unroll
    for (int ks = 0; ks < 4; ++ks)
      a3[ks] = *(const f16x8*)(base + ((ks * 64 + j * 16) ^ sw));
  }
  f32x4 acc3 = {};
  const unsigned short* wqb = wqvh + (size_t)(nt * 16 + l15) * MD + j * 8;
  #pragma unroll
  for (int ks = 0; ks < 4; ++ks) {
    f16x8 bf = *(const f16x8*)(wqb + ks * 32);
    acc3 = __builtin_amdgcn_mfma_f32_16x16x32_f16(a3[ks], bf, acc3, 0, 0, 0);
  }
  {
    const int col = nt * 16 + l15;
    if (col < 2 * NH) {
      const float badd = (col < NH) ? 0.f : bvg[col - NH];
      const size_t plane = (size_t)col * SB;
      #pragma unroll
      for (int r = 0; r < 4; ++r) {
        int s = m0 + rh * 16 + j * 4 + r;
        lv[plane + s] = acc3[r] + badd;
      }
    }
  }
}

// ---------------- sliding-window softmax + per-chunk max ----------------
__global__ void windows_k(const float* __restrict__ lv, const int* __restrict__ mask,
                          float* __restrict__ partial) {
  const int chunk = blockIdx.x, b = blockIdx.y, h = blockIdx.z;
  const int t0 = chunk * 256;
  const int tid = threadIdx.x;
  __shared__ float lsh[272], vsh[272];
  const float* lp = lv + (size_t)h * SB + b * SLEN;
  const float* vp = lv + (size_t)(NH + h) * SB + b * SLEN;
  const int* mp = mask + b * SLEN;
  for (int i = tid; i < 256 + WIN - 1; i += 256) {
    int t = t0 + i;
    if (t < SLEN) {
      float l = lp[t];
      if (mp[t] == 0) l = NEGV;
      lsh[i] = l; vsh[i] = vp[t];
    }
  }
  __syncthreads();
  float wmax = -INFINITY;
  int t = t0 + tid;
  if (t < TLEN) {
    float m = lsh[tid];
    #pragma unroll
    for (int jj = 1; jj < WIN; ++jj) m = fmaxf(m, lsh[tid + jj]);
    float den = 0.f, num = 0.f;
    #pragma unroll
    for (int jj = 0; jj < WIN; ++jj) {
      float e = __expf(lsh[tid + jj] - m);
      den += e; num += e * vsh[tid + jj];
    }
    wmax = num / den;
  }
  #pragma unroll
  for (int o = 32; o > 0; o >>= 1) wmax = fmaxf(wmax, __shfl_down(wmax, o, 64));
  __shared__ float red[4];
  if ((tid & 63) == 0) red[tid >> 6] = wmax;
  __syncthreads();
  if (tid == 0) {
    float r = fmaxf(fmaxf(red[0], red[1]), fmaxf(red[2], red[3]));
    partial[(b * NH + h) * 16 + chunk] = r;
  }
}

// ---------------- final: max over chunks, sum heads, + bias ----------------
__global__ void finalize_k(const float* __restrict__ partial, const float* __restrict__ bias,
                           float* __restrict__ out) {
  const int tid = threadIdx.x;  // 1 block, 128 thr
  __shared__ float hm[80];
  if (tid < NB * NH) {
    float m = -INFINITY;
    #pragma unroll
    for (int c = 0; c < 16; ++c) m = fmaxf(m, partial[tid * 16 + c]);
    hm[tid] = m;
  }
  __syncthreads();
  if (tid < NB) {
    float s = bias[0];
    #pragma unroll
    for (int h = 0; h < NH; ++h) s += hm[tid * NH + h];
    out[tid] = s;
  }
}

extern "C" void kernel_launch(void* const* d_in, const int* in_sizes, int n_in,
                              void* d_out, int out_size, void* d_ws, size_t ws_size,
                              hipStream_t stream) {
  const float* x    = (const float*)d_in[0];
  const int*   mask = (const int*)d_in[1];
  const float* W1   = (const float*)d_in[2];
  const float* b1   = (const float*)d_in[3];
  const float* W2   = (const float*)d_in[4];
  const float* b2   = (const float*)d_in[5];
  const float* Wq   = (const float*)d_in[6];
  const float* Wv   = (const float*)d_in[7];
  const float* bv   = (const float*)d_in[8];
  const float* bias = (const float*)d_in[9];

  char* ws = (char*)d_ws;
  unsigned short* w1h  = (unsigned short*)ws;                   // 1,048,576 B
  unsigned short* w2h  = (unsigned short*)(ws + 1048576);       //    32,768 B
  unsigned short* wqvh = (unsigned short*)(ws + 1081344);       //     8,192 B
  float* lv            = (float*)(ws + 1089536);                // 20*32768*4 = 2,621,440 B
  float* partial       = (float*)(ws + 3710976);                //     5,120 B
  float* out = (float*)d_out;

  hipLaunchKernelGGL(convert_k, dim3(2048), dim3(256), 0, stream, W1, W2, Wq, Wv, w1h, w2h, wqvh);
  hipLaunchKernelGGL(fused_mlp, dim3(SB / 32), dim3(256), 0, stream,
                     x, b1, b2, bv, w1h, w2h, wqvh, lv);
  hipLaunchKernelGGL(windows_k, dim3(16, NB, NH), dim3(256), 0, stream, lv, mask, partial);
  hipLaunchKernelGGL(finalize_k, dim3(1), dim3(128), 0, stream, partial, bias, out);
}